// Round 2
// baseline (668.756 us; speedup 1.0000x reference)
//
#include <hip/hip_runtime.h>

// YOLO v1 loss: BATCH=16384, S=7, B=2, C=20, D=30 floats per cell.
// NCELLS = 16384*49 = 802816 = 3136 * 256 exactly.
#define NCELLS 802816
#define NBLOCKS 3136

// ws layout:
//   bytes [0,8):   2 x uint32 min-slots (init 0xFFFFFFFF)
//   bytes [8,40):  4 x double accumulators {loc_sq, hit, noobj, cls} (init 0)

__global__ __launch_bounds__(256) void yolo_main_kernel(
    const float* __restrict__ pred, const float* __restrict__ targ,
    unsigned* __restrict__ minslots, double* __restrict__ acc)
{
    const int tid  = threadIdx.x;
    const int cell = blockIdx.x * 256 + tid;

    // ---- load 30 pred + 30 target floats as float2 (8B-aligned) ----
    float pv[30], tv[30];
    const float2* p2 = reinterpret_cast<const float2*>(pred) + (size_t)cell * 15;
    const float2* t2 = reinterpret_cast<const float2*>(targ) + (size_t)cell * 15;
#pragma unroll
    for (int i = 0; i < 15; ++i) { float2 v = p2[i]; pv[2*i] = v.x; pv[2*i+1] = v.y; }
#pragma unroll
    for (int i = 0; i < 15; ++i) { float2 v = t2[i]; tv[2*i] = v.x; tv[2*i+1] = v.y; }

    const float obj = (tv[0] == 1.0f) ? 1.0f : 0.0f;

    // ---- class loss ----
    float cls = 0.0f;
#pragma unroll
    for (int i = 10; i < 30; ++i) { float d = pv[i] - tv[i]; cls = fmaf(d, d, cls); }
    cls *= obj;

    // ---- gt box 0 corners (mirrors reference arithmetic) ----
    const float g0x = tv[2] / 7.0f - 0.5f * tv[4];
    const float g0y = tv[3] / 7.0f - 0.5f * tv[5];
    const float g1x = tv[2] / 7.0f + 0.5f * tv[4];
    const float g1y = tv[3] / 7.0f + 0.5f * tv[5];
    const float area_g = (g1x - g0x) * (g1y - g0y);

    // ---- IoUs for both pred boxes vs gt box 0 ----
    float iou[2];
#pragma unroll
    for (int b = 0; b < 2; ++b) {
        const float px = pv[2 + 4*b], py = pv[3 + 4*b];
        const float pw = pv[4 + 4*b], ph = pv[5 + 4*b];
        const float a0x = px / 7.0f - 0.5f * pw, a0y = py / 7.0f - 0.5f * ph;
        const float a1x = px / 7.0f + 0.5f * pw, a1y = py / 7.0f + 0.5f * ph;
        const float ltx = fmaxf(a0x, g0x), lty = fmaxf(a0y, g0y);
        const float rbx = fminf(a1x, g1x), rby = fminf(a1y, g1y);
        const float w = fmaxf(rbx - ltx, 0.0f), h = fmaxf(rby - lty, 0.0f);
        const float inter  = w * h;
        const float area_a = (a1x - a0x) * (a1y - a0y);
        iou[b] = inter / (area_a + area_g - inter);
    }
    // jnp.argmax tie-break: first index wins
    const int resp = (iou[1] > iou[0]) ? 1 : 0;

    float hit = 0.0f, noobj = 0.0f, loc_sq = 0.0f;
#pragma unroll
    for (int b = 0; b < 2; ++b) {
        const bool m = (obj != 0.0f) && (b == resp);
        const float pc = pv[b];
        if (m) {
            const float d = pc - iou[b];
            hit = fmaf(d, d, hit);
            float sq = 0.0f;
#pragma unroll
            for (int i = 0; i < 4; ++i) {
                const float a = pv[2 + 4*b + i], g = tv[2 + 4*b + i];
                const float ds = sqrtf(a) - sqrtf(g);
                sq = fmaf(ds, ds, sq);
            }
            loc_sq += sq;
            // cascading atomicMin: global min -> slot0, second-min -> slot1
            const unsigned idx = (unsigned)(cell * 2 + b);
            const unsigned o = atomicMin(&minslots[0], idx);
            const unsigned loser = (o > idx) ? o : idx;
            if (loser != 0xFFFFFFFFu) atomicMin(&minslots[1], loser);
        } else {
            noobj = fmaf(pc, pc, noobj);
        }
    }

    // ---- block reduction (LDS tree) ----
    __shared__ float sred[4][256];
    sred[0][tid] = loc_sq; sred[1][tid] = hit; sred[2][tid] = noobj; sred[3][tid] = cls;
    __syncthreads();
#pragma unroll
    for (int s = 128; s > 0; s >>= 1) {
        if (tid < s) {
            sred[0][tid] += sred[0][tid + s];
            sred[1][tid] += sred[1][tid + s];
            sred[2][tid] += sred[2][tid + s];
            sred[3][tid] += sred[3][tid + s];
        }
        __syncthreads();
    }
    if (tid == 0) {
        atomicAdd(&acc[0], (double)sred[0][0]);
        atomicAdd(&acc[1], (double)sred[1][0]);
        atomicAdd(&acc[2], (double)sred[2][0]);
        atomicAdd(&acc[3], (double)sred[3][0]);
    }
}

__global__ void yolo_finalize_kernel(
    const float* __restrict__ pred, const float* __restrict__ targ,
    const unsigned* __restrict__ minslots, const double* __restrict__ acc,
    float* __restrict__ out)
{
    double loc = acc[0];
    const double hit = acc[1], noobj = acc[2], cls = acc[3];
    // first two responsible boxes (global flat order) use plain instead of sq
#pragma unroll
    for (int s = 0; s < 2; ++s) {
        const unsigned idx = minslots[s];
        if (idx != 0xFFFFFFFFu) {
            const int cell = (int)(idx >> 1);
            const int b    = (int)(idx & 1u);
            const float* p = pred + (size_t)cell * 30 + 2 + 4*b;
            const float* t = targ + (size_t)cell * 30 + 2 + 4*b;
            float plain = 0.0f, sq = 0.0f;
#pragma unroll
            for (int i = 0; i < 4; ++i) {
                const float a = p[i], g = t[i];
                const float dd = a - g;  plain = fmaf(dd, dd, plain);
                const float ds = sqrtf(a) - sqrtf(g); sq = fmaf(ds, ds, sq);
            }
            loc += (double)plain - (double)sq;
        }
    }
    const double total = (5.0 * loc + hit + 0.5 * noobj + cls) / 16384.0;
    out[0] = (float)total;
}

extern "C" void kernel_launch(void* const* d_in, const int* in_sizes, int n_in,
                              void* d_out, int out_size, void* d_ws, size_t ws_size,
                              hipStream_t stream) {
    const float* pred = (const float*)d_in[0];
    const float* targ = (const float*)d_in[1];
    float* out = (float*)d_out;

    unsigned* minslots = (unsigned*)d_ws;
    double* acc = (double*)((char*)d_ws + 8);

    hipMemsetAsync(minslots, 0xFF, 8, stream);          // min-slots = 0xFFFFFFFF
    hipMemsetAsync(acc, 0, 4 * sizeof(double), stream); // accumulators = 0

    yolo_main_kernel<<<NBLOCKS, 256, 0, stream>>>(pred, targ, minslots, acc);
    yolo_finalize_kernel<<<1, 1, 0, stream>>>(pred, targ, minslots, acc, out);
}

// Round 3
// 46.157 us; speedup vs baseline: 14.4887x; 14.4887x over previous
//
#include <hip/hip_runtime.h>

// YOLO v1 loss: BATCH=16384, S=7, B=2, C=20, D=30 floats per cell.
// NCELLS = 16384*49 = 802816 = 3136 * 256 exactly.
#define NCELLS 802816
#define NBLOCKS 3136

// ws layout (all written by main kernel every call -> no init needed):
//   float sums[4][NBLOCKS]   at byte 0            (loc_sq, hit, noobj, cls)
//   uint  mins[2][NBLOCKS]   at byte 4*4*NBLOCKS  (min, second-min contained idx)
#define SUMS_OFF 0
#define MINS_OFF (4 * NBLOCKS)

__device__ __forceinline__ void merge2(unsigned& a1, unsigned& a2,
                                       unsigned b1, unsigned b2) {
    // (a1<=a2), (b1<=b2) -> top-2 smallest of the union
    const unsigned n1 = min(a1, b1);
    const unsigned n2 = min(max(a1, b1), min(a2, b2));
    a1 = n1; a2 = n2;
}

__global__ __launch_bounds__(256) void yolo_main_kernel(
    const float* __restrict__ pred, const float* __restrict__ targ,
    float* __restrict__ ws_sums, unsigned* __restrict__ ws_mins)
{
    const int tid  = threadIdx.x;
    const int cell = blockIdx.x * 256 + tid;

    // ---- load 30 pred + 30 target floats as float2 (8B-aligned) ----
    float pv[30], tv[30];
    const float2* p2 = reinterpret_cast<const float2*>(pred) + (size_t)cell * 15;
    const float2* t2 = reinterpret_cast<const float2*>(targ) + (size_t)cell * 15;
#pragma unroll
    for (int i = 0; i < 15; ++i) { float2 v = p2[i]; pv[2*i] = v.x; pv[2*i+1] = v.y; }
#pragma unroll
    for (int i = 0; i < 15; ++i) { float2 v = t2[i]; tv[2*i] = v.x; tv[2*i+1] = v.y; }

    const float obj = (tv[0] == 1.0f) ? 1.0f : 0.0f;

    // ---- class loss ----
    float cls = 0.0f;
#pragma unroll
    for (int i = 10; i < 30; ++i) { float d = pv[i] - tv[i]; cls = fmaf(d, d, cls); }
    cls *= obj;

    // ---- gt box 0 corners (mirrors reference arithmetic) ----
    const float g0x = tv[2] / 7.0f - 0.5f * tv[4];
    const float g0y = tv[3] / 7.0f - 0.5f * tv[5];
    const float g1x = tv[2] / 7.0f + 0.5f * tv[4];
    const float g1y = tv[3] / 7.0f + 0.5f * tv[5];
    const float area_g = (g1x - g0x) * (g1y - g0y);

    // ---- IoUs for both pred boxes vs gt box 0 ----
    float iou[2];
#pragma unroll
    for (int b = 0; b < 2; ++b) {
        const float px = pv[2 + 4*b], py = pv[3 + 4*b];
        const float pw = pv[4 + 4*b], ph = pv[5 + 4*b];
        const float a0x = px / 7.0f - 0.5f * pw, a0y = py / 7.0f - 0.5f * ph;
        const float a1x = px / 7.0f + 0.5f * pw, a1y = py / 7.0f + 0.5f * ph;
        const float ltx = fmaxf(a0x, g0x), lty = fmaxf(a0y, g0y);
        const float rbx = fminf(a1x, g1x), rby = fminf(a1y, g1y);
        const float w = fmaxf(rbx - ltx, 0.0f), h = fmaxf(rby - lty, 0.0f);
        const float inter  = w * h;
        const float area_a = (a1x - a0x) * (a1y - a0y);
        iou[b] = inter / (area_a + area_g - inter);
    }
    // jnp.argmax tie-break: first index wins
    const int resp = (iou[1] > iou[0]) ? 1 : 0;

    float hit = 0.0f, noobj = 0.0f, loc_sq = 0.0f;
    unsigned cand = 0xFFFFFFFFu;   // this thread's contained-box flat index (<=1 per cell)
#pragma unroll
    for (int b = 0; b < 2; ++b) {
        const bool m = (obj != 0.0f) && (b == resp);
        const float pc = pv[b];
        if (m) {
            const float d = pc - iou[b];
            hit = fmaf(d, d, hit);
            float sq = 0.0f;
#pragma unroll
            for (int i = 0; i < 4; ++i) {
                const float a = pv[2 + 4*b + i], g = tv[2 + 4*b + i];
                const float ds = sqrtf(a) - sqrtf(g);
                sq = fmaf(ds, ds, sq);
            }
            loc_sq += sq;
            cand = (unsigned)(cell * 2 + b);
        } else {
            noobj = fmaf(pc, pc, noobj);
        }
    }

    // ---- block reduction (LDS tree): 4 float sums + (min, 2nd-min) ----
    __shared__ float sred[4][256];
    __shared__ unsigned sm1[256], sm2[256];
    sred[0][tid] = loc_sq; sred[1][tid] = hit; sred[2][tid] = noobj; sred[3][tid] = cls;
    sm1[tid] = cand; sm2[tid] = 0xFFFFFFFFu;
    __syncthreads();
#pragma unroll
    for (int s = 128; s > 0; s >>= 1) {
        if (tid < s) {
            sred[0][tid] += sred[0][tid + s];
            sred[1][tid] += sred[1][tid + s];
            sred[2][tid] += sred[2][tid + s];
            sred[3][tid] += sred[3][tid + s];
            unsigned a1 = sm1[tid], a2 = sm2[tid];
            merge2(a1, a2, sm1[tid + s], sm2[tid + s]);
            sm1[tid] = a1; sm2[tid] = a2;
        }
        __syncthreads();
    }
    if (tid == 0) {
        ws_sums[0 * NBLOCKS + blockIdx.x] = sred[0][0];
        ws_sums[1 * NBLOCKS + blockIdx.x] = sred[1][0];
        ws_sums[2 * NBLOCKS + blockIdx.x] = sred[2][0];
        ws_sums[3 * NBLOCKS + blockIdx.x] = sred[3][0];
        ws_mins[0 * NBLOCKS + blockIdx.x] = sm1[0];
        ws_mins[1 * NBLOCKS + blockIdx.x] = sm2[0];
    }
}

__global__ __launch_bounds__(256) void yolo_finalize_kernel(
    const float* __restrict__ pred, const float* __restrict__ targ,
    const float* __restrict__ ws_sums, const unsigned* __restrict__ ws_mins,
    float* __restrict__ out)
{
    const int tid = threadIdx.x;
    double s0 = 0.0, s1 = 0.0, s2 = 0.0, s3 = 0.0;
    unsigned m1 = 0xFFFFFFFFu, m2 = 0xFFFFFFFFu;
    for (int i = tid; i < NBLOCKS; i += 256) {
        s0 += (double)ws_sums[0 * NBLOCKS + i];
        s1 += (double)ws_sums[1 * NBLOCKS + i];
        s2 += (double)ws_sums[2 * NBLOCKS + i];
        s3 += (double)ws_sums[3 * NBLOCKS + i];
        merge2(m1, m2, ws_mins[0 * NBLOCKS + i], ws_mins[1 * NBLOCKS + i]);
    }
    __shared__ double dred[4][256];
    __shared__ unsigned fm1[256], fm2[256];
    dred[0][tid] = s0; dred[1][tid] = s1; dred[2][tid] = s2; dred[3][tid] = s3;
    fm1[tid] = m1; fm2[tid] = m2;
    __syncthreads();
#pragma unroll
    for (int s = 128; s > 0; s >>= 1) {
        if (tid < s) {
            dred[0][tid] += dred[0][tid + s];
            dred[1][tid] += dred[1][tid + s];
            dred[2][tid] += dred[2][tid + s];
            dred[3][tid] += dred[3][tid + s];
            unsigned a1 = fm1[tid], a2 = fm2[tid];
            merge2(a1, a2, fm1[tid + s], fm2[tid + s]);
            fm1[tid] = a1; fm2[tid] = a2;
        }
        __syncthreads();
    }
    if (tid == 0) {
        double loc = dred[0][0];
        const double hit = dred[1][0], noobj = dred[2][0], cls = dred[3][0];
        const unsigned mm[2] = { fm1[0], fm2[0] };
        // first two responsible boxes (global flat order) use plain instead of sq
#pragma unroll
        for (int s = 0; s < 2; ++s) {
            const unsigned idx = mm[s];
            if (idx != 0xFFFFFFFFu) {
                const int cell = (int)(idx >> 1);
                const int b    = (int)(idx & 1u);
                const float* p = pred + (size_t)cell * 30 + 2 + 4*b;
                const float* t = targ + (size_t)cell * 30 + 2 + 4*b;
                float plain = 0.0f, sq = 0.0f;
#pragma unroll
                for (int i = 0; i < 4; ++i) {
                    const float a = p[i], g = t[i];
                    const float dd = a - g;  plain = fmaf(dd, dd, plain);
                    const float ds = sqrtf(a) - sqrtf(g); sq = fmaf(ds, ds, sq);
                }
                loc += (double)plain - (double)sq;
            }
        }
        const double total = (5.0 * loc + hit + 0.5 * noobj + cls) / 16384.0;
        out[0] = (float)total;
    }
}

extern "C" void kernel_launch(void* const* d_in, const int* in_sizes, int n_in,
                              void* d_out, int out_size, void* d_ws, size_t ws_size,
                              hipStream_t stream) {
    const float* pred = (const float*)d_in[0];
    const float* targ = (const float*)d_in[1];
    float* out = (float*)d_out;

    float* ws_sums = (float*)d_ws;                       // 4*NBLOCKS floats
    unsigned* ws_mins = (unsigned*)((char*)d_ws + sizeof(float) * 4 * NBLOCKS);

    yolo_main_kernel<<<NBLOCKS, 256, 0, stream>>>(pred, targ, ws_sums, ws_mins);
    yolo_finalize_kernel<<<1, 256, 0, stream>>>(pred, targ, ws_sums, ws_mins, out);
}

// Round 4
// 45.566 us; speedup vs baseline: 14.6765x; 1.0130x over previous
//
#include <hip/hip_runtime.h>
#include <stdint.h>

// YOLO v1 loss: BATCH=16384, S=7, B=2, C=20, D=30 floats per cell.
// NCELLS = 16384*49 = 802816 = 3136 * 256 exactly.
#define NCELLS 802816
#define NBLOCKS 3136
#define F4_PER_TILE 1920   // 256 cells * 30 floats / 4

// async global->LDS, 16B per lane. LDS dest is wave-uniform base + lane*16.
#define ASYNC_CP16(gsrc, ldst)                                                     \
    __builtin_amdgcn_global_load_lds(                                              \
        (const __attribute__((address_space(1))) unsigned int*)(gsrc),             \
        (__attribute__((address_space(3))) unsigned int*)(ldst), 16, 0, 0)

__device__ __forceinline__ void merge2(unsigned& a1, unsigned& a2,
                                       unsigned b1, unsigned b2) {
    // (a1<=a2), (b1<=b2) -> top-2 smallest of the union
    const unsigned n1 = min(a1, b1);
    const unsigned n2 = min(max(a1, b1), min(a2, b2));
    a1 = n1; a2 = n2;
}

__global__ __launch_bounds__(256) void yolo_main_kernel(
    const float* __restrict__ pred, const float* __restrict__ targ,
    float* __restrict__ ws_sums, unsigned* __restrict__ ws_mins)
{
    // smem layout: [0,7680) pred tile floats, [7680,15360) targ tile floats.
    // After compute, first 1536 floats are reused for the block reduction.
    __shared__ __align__(16) float smem[15360];
    float* sp = smem;
    float* st = smem + 7680;

    const int tid = threadIdx.x;
    const int w   = tid >> 6;           // wave id (0..3)

    // ---- coalesced async fill: 1920 float4 per tensor ----
    const float4* p4 = reinterpret_cast<const float4*>(pred) + (size_t)blockIdx.x * F4_PER_TILE;
    const float4* t4 = reinterpret_cast<const float4*>(targ) + (size_t)blockIdx.x * F4_PER_TILE;
#pragma unroll
    for (int k = 0; k < 8; ++k) {
        const int j = tid + 256 * k;
        if (j < F4_PER_TILE) {
            // LDS float offset for this wave-instr: 256*w + 1024*k (HW adds lane*16B)
            ASYNC_CP16(p4 + j, sp + 256 * w + 1024 * k);
            ASYNC_CP16(t4 + j, st + 256 * w + 1024 * k);
        }
    }
    __syncthreads();   // drains vmcnt before barrier

    // ---- read this thread's 30+30 floats from LDS ----
    float pv[30], tv[30];
    const float2* spp = reinterpret_cast<const float2*>(sp) + tid * 15;
    const float2* stp = reinterpret_cast<const float2*>(st) + tid * 15;
#pragma unroll
    for (int i = 0; i < 15; ++i) { float2 v = spp[i]; pv[2*i] = v.x; pv[2*i+1] = v.y; }
#pragma unroll
    for (int i = 0; i < 15; ++i) { float2 v = stp[i]; tv[2*i] = v.x; tv[2*i+1] = v.y; }

    const int cell = blockIdx.x * 256 + tid;
    const float obj = (tv[0] == 1.0f) ? 1.0f : 0.0f;

    // ---- class loss ----
    float cls = 0.0f;
#pragma unroll
    for (int i = 10; i < 30; ++i) { float d = pv[i] - tv[i]; cls = fmaf(d, d, cls); }
    cls *= obj;

    // ---- gt box 0 corners (mirrors reference arithmetic) ----
    const float g0x = tv[2] / 7.0f - 0.5f * tv[4];
    const float g0y = tv[3] / 7.0f - 0.5f * tv[5];
    const float g1x = tv[2] / 7.0f + 0.5f * tv[4];
    const float g1y = tv[3] / 7.0f + 0.5f * tv[5];
    const float area_g = (g1x - g0x) * (g1y - g0y);

    // ---- IoUs for both pred boxes vs gt box 0 ----
    float iou[2];
#pragma unroll
    for (int b = 0; b < 2; ++b) {
        const float px = pv[2 + 4*b], py = pv[3 + 4*b];
        const float pw = pv[4 + 4*b], ph = pv[5 + 4*b];
        const float a0x = px / 7.0f - 0.5f * pw, a0y = py / 7.0f - 0.5f * ph;
        const float a1x = px / 7.0f + 0.5f * pw, a1y = py / 7.0f + 0.5f * ph;
        const float ltx = fmaxf(a0x, g0x), lty = fmaxf(a0y, g0y);
        const float rbx = fminf(a1x, g1x), rby = fminf(a1y, g1y);
        const float ww = fmaxf(rbx - ltx, 0.0f), hh = fmaxf(rby - lty, 0.0f);
        const float inter  = ww * hh;
        const float area_a = (a1x - a0x) * (a1y - a0y);
        iou[b] = inter / (area_a + area_g - inter);
    }
    // jnp.argmax tie-break: first index wins
    const int resp = (iou[1] > iou[0]) ? 1 : 0;

    float hit = 0.0f, noobj = 0.0f, loc_sq = 0.0f;
    unsigned cand = 0xFFFFFFFFu;   // this thread's contained-box flat index (<=1 per cell)
#pragma unroll
    for (int b = 0; b < 2; ++b) {
        const bool m = (obj != 0.0f) && (b == resp);
        const float pc = pv[b];
        if (m) {
            const float d = pc - iou[b];
            hit = fmaf(d, d, hit);
            float sq = 0.0f;
#pragma unroll
            for (int i = 0; i < 4; ++i) {
                const float a = pv[2 + 4*b + i], g = tv[2 + 4*b + i];
                const float ds = sqrtf(a) - sqrtf(g);
                sq = fmaf(ds, ds, sq);
            }
            loc_sq += sq;
            cand = (unsigned)(cell * 2 + b);
        } else {
            noobj = fmaf(pc, pc, noobj);
        }
    }

    // ---- block reduction: overlay LDS (staging data fully consumed) ----
    __syncthreads();
    float* R = smem;                                   // 4 arrays of 256 floats
    unsigned* M1 = (unsigned*)(smem + 1024);           // 256 uints
    unsigned* M2 = (unsigned*)(smem + 1280);           // 256 uints
    R[0*256 + tid] = loc_sq; R[1*256 + tid] = hit;
    R[2*256 + tid] = noobj;  R[3*256 + tid] = cls;
    M1[tid] = cand; M2[tid] = 0xFFFFFFFFu;
    __syncthreads();
#pragma unroll
    for (int s = 128; s > 0; s >>= 1) {
        if (tid < s) {
            R[0*256 + tid] += R[0*256 + tid + s];
            R[1*256 + tid] += R[1*256 + tid + s];
            R[2*256 + tid] += R[2*256 + tid + s];
            R[3*256 + tid] += R[3*256 + tid + s];
            unsigned a1 = M1[tid], a2 = M2[tid];
            merge2(a1, a2, M1[tid + s], M2[tid + s]);
            M1[tid] = a1; M2[tid] = a2;
        }
        __syncthreads();
    }
    if (tid == 0) {
        ws_sums[0 * NBLOCKS + blockIdx.x] = R[0*256];
        ws_sums[1 * NBLOCKS + blockIdx.x] = R[1*256];
        ws_sums[2 * NBLOCKS + blockIdx.x] = R[2*256];
        ws_sums[3 * NBLOCKS + blockIdx.x] = R[3*256];
        ws_mins[0 * NBLOCKS + blockIdx.x] = M1[0];
        ws_mins[1 * NBLOCKS + blockIdx.x] = M2[0];
    }
}

__global__ __launch_bounds__(256) void yolo_finalize_kernel(
    const float* __restrict__ pred, const float* __restrict__ targ,
    const float* __restrict__ ws_sums, const unsigned* __restrict__ ws_mins,
    float* __restrict__ out)
{
    const int tid = threadIdx.x;
    double s0 = 0.0, s1 = 0.0, s2 = 0.0, s3 = 0.0;
    unsigned m1 = 0xFFFFFFFFu, m2 = 0xFFFFFFFFu;
    for (int i = tid; i < NBLOCKS; i += 256) {
        s0 += (double)ws_sums[0 * NBLOCKS + i];
        s1 += (double)ws_sums[1 * NBLOCKS + i];
        s2 += (double)ws_sums[2 * NBLOCKS + i];
        s3 += (double)ws_sums[3 * NBLOCKS + i];
        merge2(m1, m2, ws_mins[0 * NBLOCKS + i], ws_mins[1 * NBLOCKS + i]);
    }
    __shared__ double dred[4][256];
    __shared__ unsigned fm1[256], fm2[256];
    dred[0][tid] = s0; dred[1][tid] = s1; dred[2][tid] = s2; dred[3][tid] = s3;
    fm1[tid] = m1; fm2[tid] = m2;
    __syncthreads();
#pragma unroll
    for (int s = 128; s > 0; s >>= 1) {
        if (tid < s) {
            dred[0][tid] += dred[0][tid + s];
            dred[1][tid] += dred[1][tid + s];
            dred[2][tid] += dred[2][tid + s];
            dred[3][tid] += dred[3][tid + s];
            unsigned a1 = fm1[tid], a2 = fm2[tid];
            merge2(a1, a2, fm1[tid + s], fm2[tid + s]);
            fm1[tid] = a1; fm2[tid] = a2;
        }
        __syncthreads();
    }
    if (tid == 0) {
        double loc = dred[0][0];
        const double hit = dred[1][0], noobj = dred[2][0], cls = dred[3][0];
        const unsigned mm[2] = { fm1[0], fm2[0] };
        // first two responsible boxes (global flat order) use plain instead of sq
#pragma unroll
        for (int s = 0; s < 2; ++s) {
            const unsigned idx = mm[s];
            if (idx != 0xFFFFFFFFu) {
                const int cell = (int)(idx >> 1);
                const int b    = (int)(idx & 1u);
                const float* p = pred + (size_t)cell * 30 + 2 + 4*b;
                const float* t = targ + (size_t)cell * 30 + 2 + 4*b;
                float plain = 0.0f, sq = 0.0f;
#pragma unroll
                for (int i = 0; i < 4; ++i) {
                    const float a = p[i], g = t[i];
                    const float dd = a - g;  plain = fmaf(dd, dd, plain);
                    const float ds = sqrtf(a) - sqrtf(g); sq = fmaf(ds, ds, sq);
                }
                loc += (double)plain - (double)sq;
            }
        }
        const double total = (5.0 * loc + hit + 0.5 * noobj + cls) / 16384.0;
        out[0] = (float)total;
    }
}

extern "C" void kernel_launch(void* const* d_in, const int* in_sizes, int n_in,
                              void* d_out, int out_size, void* d_ws, size_t ws_size,
                              hipStream_t stream) {
    const float* pred = (const float*)d_in[0];
    const float* targ = (const float*)d_in[1];
    float* out = (float*)d_out;

    float* ws_sums = (float*)d_ws;                       // 4*NBLOCKS floats
    unsigned* ws_mins = (unsigned*)((char*)d_ws + sizeof(float) * 4 * NBLOCKS);

    yolo_main_kernel<<<NBLOCKS, 256, 0, stream>>>(pred, targ, ws_sums, ws_mins);
    yolo_finalize_kernel<<<1, 256, 0, stream>>>(pred, targ, ws_sums, ws_mins, out);
}

// Round 5
// 42.673 us; speedup vs baseline: 15.6715x; 1.0678x over previous
//
#include <hip/hip_runtime.h>
#include <stdint.h>

// YOLO v1 loss: BATCH=16384, S=7, B=2, C=20, D=30 floats per cell.
// NCELLS = 802816 = 12544 blocks * 64 cells. One wave per block, barrier-free.
#define NCELLS 802816
#define NB 12544            // main-kernel blocks (64 cells each)
#define F4_PER_TILE 480     // 64 cells * 30 floats / 4 floats-per-float4

// async global->LDS, 16B per lane. LDS dest = wave-uniform base + lane*16.
#define ASYNC_CP16(gsrc, ldst)                                                     \
    __builtin_amdgcn_global_load_lds(                                              \
        (const __attribute__((address_space(1))) unsigned int*)(gsrc),             \
        (__attribute__((address_space(3))) unsigned int*)(ldst), 16, 0, 0)

__device__ __forceinline__ void merge2(unsigned& a1, unsigned& a2,
                                       unsigned b1, unsigned b2) {
    // (a1<=a2), (b1<=b2) -> two smallest of the union
    const unsigned n1 = min(a1, b1);
    const unsigned n2 = min(max(a1, b1), min(a2, b2));
    a1 = n1; a2 = n2;
}

// ws layout (SoA, all slots written every call):
//   float sums[4][NB]  at float offset 0      (loc_sq, hit, noobj, cls)
//   uint  mins[2][NB]  at float offset 4*NB   (min, second-min contained idx)

__global__ __launch_bounds__(64) void yolo_main_kernel(
    const float* __restrict__ pred, const float* __restrict__ targ,
    float* __restrict__ ws_sums, unsigned* __restrict__ ws_mins)
{
    // 64 cells * 30 floats per tensor = 1920 floats = 7680 B per tensor.
    __shared__ __align__(16) float smem[3840];
    float* sp = smem;
    float* st = smem + 1920;

    const int lane = threadIdx.x;       // 0..63, single wave

    // ---- coalesced async fill: 480 float4 per tensor (7.5 wave-instrs) ----
    const float4* p4 = reinterpret_cast<const float4*>(pred) + (size_t)blockIdx.x * F4_PER_TILE;
    const float4* t4 = reinterpret_cast<const float4*>(targ) + (size_t)blockIdx.x * F4_PER_TILE;
#pragma unroll
    for (int k = 0; k < 7; ++k) {
        ASYNC_CP16(p4 + lane + 64 * k, sp + 256 * k);
        ASYNC_CP16(t4 + lane + 64 * k, st + 256 * k);
    }
    if (lane < 32) {
        ASYNC_CP16(p4 + lane + 448, sp + 1792);
        ASYNC_CP16(t4 + lane + 448, st + 1792);
    }
    __syncthreads();   // single-wave: compiles to waitcnt drain + cheap barrier

    // ---- read this thread's 30+30 floats from LDS ----
    float pv[30], tv[30];
    const float2* spp = reinterpret_cast<const float2*>(sp) + lane * 15;
    const float2* stp = reinterpret_cast<const float2*>(st) + lane * 15;
#pragma unroll
    for (int i = 0; i < 15; ++i) { float2 v = spp[i]; pv[2*i] = v.x; pv[2*i+1] = v.y; }
#pragma unroll
    for (int i = 0; i < 15; ++i) { float2 v = stp[i]; tv[2*i] = v.x; tv[2*i+1] = v.y; }

    const int cell = blockIdx.x * 64 + lane;
    const float obj = (tv[0] == 1.0f) ? 1.0f : 0.0f;

    // ---- class loss ----
    float cls = 0.0f;
#pragma unroll
    for (int i = 10; i < 30; ++i) { float d = pv[i] - tv[i]; cls = fmaf(d, d, cls); }
    cls *= obj;

    // ---- gt box 0 corners (mirrors reference arithmetic) ----
    const float g0x = tv[2] / 7.0f - 0.5f * tv[4];
    const float g0y = tv[3] / 7.0f - 0.5f * tv[5];
    const float g1x = tv[2] / 7.0f + 0.5f * tv[4];
    const float g1y = tv[3] / 7.0f + 0.5f * tv[5];
    const float area_g = (g1x - g0x) * (g1y - g0y);

    // ---- IoUs for both pred boxes vs gt box 0 ----
    float iou[2];
#pragma unroll
    for (int b = 0; b < 2; ++b) {
        const float px = pv[2 + 4*b], py = pv[3 + 4*b];
        const float pw = pv[4 + 4*b], ph = pv[5 + 4*b];
        const float a0x = px / 7.0f - 0.5f * pw, a0y = py / 7.0f - 0.5f * ph;
        const float a1x = px / 7.0f + 0.5f * pw, a1y = py / 7.0f + 0.5f * ph;
        const float ltx = fmaxf(a0x, g0x), lty = fmaxf(a0y, g0y);
        const float rbx = fminf(a1x, g1x), rby = fminf(a1y, g1y);
        const float ww = fmaxf(rbx - ltx, 0.0f), hh = fmaxf(rby - lty, 0.0f);
        const float inter  = ww * hh;
        const float area_a = (a1x - a0x) * (a1y - a0y);
        iou[b] = inter / (area_a + area_g - inter);
    }
    // jnp.argmax tie-break: first index wins
    const int resp = (iou[1] > iou[0]) ? 1 : 0;

    float hit = 0.0f, noobj = 0.0f, loc_sq = 0.0f;
    unsigned m1 = 0xFFFFFFFFu, m2 = 0xFFFFFFFFu;  // contained idx: <=1 per cell
#pragma unroll
    for (int b = 0; b < 2; ++b) {
        const bool m = (obj != 0.0f) && (b == resp);
        const float pc = pv[b];
        if (m) {
            const float d = pc - iou[b];
            hit = fmaf(d, d, hit);
            float sq = 0.0f;
#pragma unroll
            for (int i = 0; i < 4; ++i) {
                const float a = pv[2 + 4*b + i], g = tv[2 + 4*b + i];
                const float ds = sqrtf(a) - sqrtf(g);
                sq = fmaf(ds, ds, sq);
            }
            loc_sq += sq;
            m1 = (unsigned)(cell * 2 + b);
        } else {
            noobj = fmaf(pc, pc, noobj);
        }
    }

    // ---- in-wave butterfly reduction (no LDS, no barriers) ----
#pragma unroll
    for (int mask = 32; mask > 0; mask >>= 1) {
        loc_sq += __shfl_xor(loc_sq, mask);
        hit    += __shfl_xor(hit,    mask);
        noobj  += __shfl_xor(noobj,  mask);
        cls    += __shfl_xor(cls,    mask);
        const unsigned b1 = (unsigned)__shfl_xor((int)m1, mask);
        const unsigned b2 = (unsigned)__shfl_xor((int)m2, mask);
        merge2(m1, m2, b1, b2);
    }
    if (lane == 0) {
        ws_sums[0 * NB + blockIdx.x] = loc_sq;
        ws_sums[1 * NB + blockIdx.x] = hit;
        ws_sums[2 * NB + blockIdx.x] = noobj;
        ws_sums[3 * NB + blockIdx.x] = cls;
        ws_mins[0 * NB + blockIdx.x] = m1;
        ws_mins[1 * NB + blockIdx.x] = m2;
    }
}

__global__ __launch_bounds__(1024) void yolo_finalize_kernel(
    const float* __restrict__ pred, const float* __restrict__ targ,
    const float* __restrict__ ws_sums, const unsigned* __restrict__ ws_mins,
    float* __restrict__ out)
{
    const int tid = threadIdx.x;
    double s0 = 0.0, s1 = 0.0, s2 = 0.0, s3 = 0.0;
    unsigned m1 = 0xFFFFFFFFu, m2 = 0xFFFFFFFFu;
    for (int i = tid; i < NB; i += 1024) {
        s0 += (double)ws_sums[0 * NB + i];
        s1 += (double)ws_sums[1 * NB + i];
        s2 += (double)ws_sums[2 * NB + i];
        s3 += (double)ws_sums[3 * NB + i];
        merge2(m1, m2, ws_mins[0 * NB + i], ws_mins[1 * NB + i]);
    }
    __shared__ double dred[4][1024];
    __shared__ unsigned fm1[1024], fm2[1024];
    dred[0][tid] = s0; dred[1][tid] = s1; dred[2][tid] = s2; dred[3][tid] = s3;
    fm1[tid] = m1; fm2[tid] = m2;
    __syncthreads();
#pragma unroll
    for (int s = 512; s > 0; s >>= 1) {
        if (tid < s) {
            dred[0][tid] += dred[0][tid + s];
            dred[1][tid] += dred[1][tid + s];
            dred[2][tid] += dred[2][tid + s];
            dred[3][tid] += dred[3][tid + s];
            unsigned a1 = fm1[tid], a2 = fm2[tid];
            merge2(a1, a2, fm1[tid + s], fm2[tid + s]);
            fm1[tid] = a1; fm2[tid] = a2;
        }
        __syncthreads();
    }
    if (tid == 0) {
        double loc = dred[0][0];
        const double hit = dred[1][0], noobj = dred[2][0], cls = dred[3][0];
        const unsigned mm[2] = { fm1[0], fm2[0] };
        // first two responsible boxes (global flat order) use plain instead of sq
#pragma unroll
        for (int s = 0; s < 2; ++s) {
            const unsigned idx = mm[s];
            if (idx != 0xFFFFFFFFu) {
                const int cell = (int)(idx >> 1);
                const int b    = (int)(idx & 1u);
                const float* p = pred + (size_t)cell * 30 + 2 + 4*b;
                const float* t = targ + (size_t)cell * 30 + 2 + 4*b;
                float plain = 0.0f, sq = 0.0f;
#pragma unroll
                for (int i = 0; i < 4; ++i) {
                    const float a = p[i], g = t[i];
                    const float dd = a - g;  plain = fmaf(dd, dd, plain);
                    const float ds = sqrtf(a) - sqrtf(g); sq = fmaf(ds, ds, sq);
                }
                loc += (double)plain - (double)sq;
            }
        }
        const double total = (5.0 * loc + hit + 0.5 * noobj + cls) / 16384.0;
        out[0] = (float)total;
    }
}

extern "C" void kernel_launch(void* const* d_in, const int* in_sizes, int n_in,
                              void* d_out, int out_size, void* d_ws, size_t ws_size,
                              hipStream_t stream) {
    const float* pred = (const float*)d_in[0];
    const float* targ = (const float*)d_in[1];
    float* out = (float*)d_out;

    float* ws_sums = (float*)d_ws;                                   // 4*NB floats
    unsigned* ws_mins = (unsigned*)((char*)d_ws + sizeof(float) * 4 * NB);  // 2*NB uints

    yolo_main_kernel<<<NB, 64, 0, stream>>>(pred, targ, ws_sums, ws_mins);
    yolo_finalize_kernel<<<1, 1024, 0, stream>>>(pred, targ, ws_sums, ws_mins, out);
}

// Round 6
// 41.549 us; speedup vs baseline: 16.0957x; 1.0271x over previous
//
#include <hip/hip_runtime.h>
#include <stdint.h>

// YOLO v1 loss: BATCH=16384, S=7, B=2, C=20, D=30 floats per cell.
// NCELLS = 802816 = 12544 tiles * 64 cells.
// Main: 3136 persistent 1-wave blocks, 4 tiles each (tile = blk + k*3136).
#define NCELLS 802816
#define NTILES 12544
#define GBLK 3136           // main-kernel blocks; also the partial count
#define TILES_PER_BLK 4
#define F4_PER_TILE 480     // 64 cells * 30 floats / 4 floats-per-float4

// async global->LDS, 16B per lane. LDS dest = wave-uniform base + lane*16.
#define ASYNC_CP16(gsrc, ldst)                                                     \
    __builtin_amdgcn_global_load_lds(                                              \
        (const __attribute__((address_space(1))) unsigned int*)(gsrc),             \
        (__attribute__((address_space(3))) unsigned int*)(ldst), 16, 0, 0)

__device__ __forceinline__ void merge2(unsigned& a1, unsigned& a2,
                                       unsigned b1, unsigned b2) {
    // (a1<=a2), (b1<=b2) -> two smallest of the union
    const unsigned n1 = min(a1, b1);
    const unsigned n2 = min(max(a1, b1), min(a2, b2));
    a1 = n1; a2 = n2;
}

// ws layout (SoA, every slot written every call):
//   float sums[4][GBLK]  at float offset 0       (loc_sq, hit, noobj, cls)
//   uint  mins[2][GBLK]  at float offset 4*GBLK  (min, second-min contained idx)

__global__ __launch_bounds__(64) void yolo_main_kernel(
    const float* __restrict__ pred, const float* __restrict__ targ,
    float* __restrict__ ws_sums, unsigned* __restrict__ ws_mins)
{
    // 64 cells * 30 floats per tensor = 1920 floats = 7680 B per tensor.
    __shared__ __align__(16) float smem[3840];
    float* sp = smem;
    float* st = smem + 1920;

    const int lane = threadIdx.x;       // 0..63, single wave
    const int blk  = blockIdx.x;

    float acc_loc = 0.0f, acc_hit = 0.0f, acc_noobj = 0.0f, acc_cls = 0.0f;
    unsigned m1 = 0xFFFFFFFFu, m2 = 0xFFFFFFFFu;

    for (int k = 0; k < TILES_PER_BLK; ++k) {
        const int tile = blk + k * GBLK;

        // ---- coalesced async fill: 480 float4 per tensor (7.5 wave-instrs) ----
        const float4* p4 = reinterpret_cast<const float4*>(pred) + (size_t)tile * F4_PER_TILE;
        const float4* t4 = reinterpret_cast<const float4*>(targ) + (size_t)tile * F4_PER_TILE;
#pragma unroll
        for (int q = 0; q < 7; ++q) {
            ASYNC_CP16(p4 + lane + 64 * q, sp + 256 * q);
            ASYNC_CP16(t4 + lane + 64 * q, st + 256 * q);
        }
        if (lane < 32) {
            ASYNC_CP16(p4 + lane + 448, sp + 1792);
            ASYNC_CP16(t4 + lane + 448, st + 1792);
        }
        __syncthreads();   // fills landed (vmcnt drain; single-wave barrier)

        // ---- read this thread's 30+30 floats from LDS ----
        float pv[30], tv[30];
        const float2* spp = reinterpret_cast<const float2*>(sp) + lane * 15;
        const float2* stp = reinterpret_cast<const float2*>(st) + lane * 15;
#pragma unroll
        for (int i = 0; i < 15; ++i) { float2 v = spp[i]; pv[2*i] = v.x; pv[2*i+1] = v.y; }
#pragma unroll
        for (int i = 0; i < 15; ++i) { float2 v = stp[i]; tv[2*i] = v.x; tv[2*i+1] = v.y; }

        const int cell = tile * 64 + lane;
        const float obj = (tv[0] == 1.0f) ? 1.0f : 0.0f;

        // ---- class loss ----
        float cls = 0.0f;
#pragma unroll
        for (int i = 10; i < 30; ++i) { float d = pv[i] - tv[i]; cls = fmaf(d, d, cls); }
        acc_cls = fmaf(cls, obj, acc_cls);

        // ---- gt box 0 corners (mirrors reference arithmetic) ----
        const float g0x = tv[2] / 7.0f - 0.5f * tv[4];
        const float g0y = tv[3] / 7.0f - 0.5f * tv[5];
        const float g1x = tv[2] / 7.0f + 0.5f * tv[4];
        const float g1y = tv[3] / 7.0f + 0.5f * tv[5];
        const float area_g = (g1x - g0x) * (g1y - g0y);

        // ---- IoUs for both pred boxes vs gt box 0 ----
        float iou[2];
#pragma unroll
        for (int b = 0; b < 2; ++b) {
            const float px = pv[2 + 4*b], py = pv[3 + 4*b];
            const float pw = pv[4 + 4*b], ph = pv[5 + 4*b];
            const float a0x = px / 7.0f - 0.5f * pw, a0y = py / 7.0f - 0.5f * ph;
            const float a1x = px / 7.0f + 0.5f * pw, a1y = py / 7.0f + 0.5f * ph;
            const float ltx = fmaxf(a0x, g0x), lty = fmaxf(a0y, g0y);
            const float rbx = fminf(a1x, g1x), rby = fminf(a1y, g1y);
            const float ww = fmaxf(rbx - ltx, 0.0f), hh = fmaxf(rby - lty, 0.0f);
            const float inter  = ww * hh;
            const float area_a = (a1x - a0x) * (a1y - a0y);
            iou[b] = inter / (area_a + area_g - inter);
        }
        // jnp.argmax tie-break: first index wins
        const int resp = (iou[1] > iou[0]) ? 1 : 0;

#pragma unroll
        for (int b = 0; b < 2; ++b) {
            const bool m = (obj != 0.0f) && (b == resp);
            const float pc = pv[b];
            if (m) {
                const float d = pc - iou[b];
                acc_hit = fmaf(d, d, acc_hit);
                float sq = 0.0f;
#pragma unroll
                for (int i = 0; i < 4; ++i) {
                    const float a = pv[2 + 4*b + i], g = tv[2 + 4*b + i];
                    const float ds = sqrtf(a) - sqrtf(g);
                    sq = fmaf(ds, ds, sq);
                }
                acc_loc += sq;
                merge2(m1, m2, (unsigned)(cell * 2 + b), 0xFFFFFFFFu);
            } else {
                acc_noobj = fmaf(pc, pc, acc_noobj);
            }
        }

        __syncthreads();   // ds_reads done before next tile's fills overwrite LDS
    }

    // ---- in-wave butterfly reduction (no LDS, no barriers) ----
#pragma unroll
    for (int mask = 32; mask > 0; mask >>= 1) {
        acc_loc   += __shfl_xor(acc_loc,   mask);
        acc_hit   += __shfl_xor(acc_hit,   mask);
        acc_noobj += __shfl_xor(acc_noobj, mask);
        acc_cls   += __shfl_xor(acc_cls,   mask);
        const unsigned b1 = (unsigned)__shfl_xor((int)m1, mask);
        const unsigned b2 = (unsigned)__shfl_xor((int)m2, mask);
        merge2(m1, m2, b1, b2);
    }
    if (lane == 0) {
        ws_sums[0 * GBLK + blk] = acc_loc;
        ws_sums[1 * GBLK + blk] = acc_hit;
        ws_sums[2 * GBLK + blk] = acc_noobj;
        ws_sums[3 * GBLK + blk] = acc_cls;
        ws_mins[0 * GBLK + blk] = m1;
        ws_mins[1 * GBLK + blk] = m2;
    }
}

__global__ __launch_bounds__(1024) void yolo_finalize_kernel(
    const float* __restrict__ pred, const float* __restrict__ targ,
    const float* __restrict__ ws_sums, const unsigned* __restrict__ ws_mins,
    float* __restrict__ out)
{
    const int tid = threadIdx.x;
    double s0 = 0.0, s1 = 0.0, s2 = 0.0, s3 = 0.0;
    unsigned m1 = 0xFFFFFFFFu, m2 = 0xFFFFFFFFu;
    for (int i = tid; i < GBLK; i += 1024) {
        s0 += (double)ws_sums[0 * GBLK + i];
        s1 += (double)ws_sums[1 * GBLK + i];
        s2 += (double)ws_sums[2 * GBLK + i];
        s3 += (double)ws_sums[3 * GBLK + i];
        merge2(m1, m2, ws_mins[0 * GBLK + i], ws_mins[1 * GBLK + i]);
    }
    __shared__ double dred[4][1024];
    __shared__ unsigned fm1[1024], fm2[1024];
    dred[0][tid] = s0; dred[1][tid] = s1; dred[2][tid] = s2; dred[3][tid] = s3;
    fm1[tid] = m1; fm2[tid] = m2;
    __syncthreads();
#pragma unroll
    for (int s = 512; s > 0; s >>= 1) {
        if (tid < s) {
            dred[0][tid] += dred[0][tid + s];
            dred[1][tid] += dred[1][tid + s];
            dred[2][tid] += dred[2][tid + s];
            dred[3][tid] += dred[3][tid + s];
            unsigned a1 = fm1[tid], a2 = fm2[tid];
            merge2(a1, a2, fm1[tid + s], fm2[tid + s]);
            fm1[tid] = a1; fm2[tid] = a2;
        }
        __syncthreads();
    }
    if (tid == 0) {
        double loc = dred[0][0];
        const double hit = dred[1][0], noobj = dred[2][0], cls = dred[3][0];
        const unsigned mm[2] = { fm1[0], fm2[0] };
        // first two responsible boxes (global flat order) use plain instead of sq
#pragma unroll
        for (int s = 0; s < 2; ++s) {
            const unsigned idx = mm[s];
            if (idx != 0xFFFFFFFFu) {
                const int cell = (int)(idx >> 1);
                const int b    = (int)(idx & 1u);
                const float* p = pred + (size_t)cell * 30 + 2 + 4*b;
                const float* t = targ + (size_t)cell * 30 + 2 + 4*b;
                float plain = 0.0f, sq = 0.0f;
#pragma unroll
                for (int i = 0; i < 4; ++i) {
                    const float a = p[i], g = t[i];
                    const float dd = a - g;  plain = fmaf(dd, dd, plain);
                    const float ds = sqrtf(a) - sqrtf(g); sq = fmaf(ds, ds, sq);
                }
                loc += (double)plain - (double)sq;
            }
        }
        const double total = (5.0 * loc + hit + 0.5 * noobj + cls) / 16384.0;
        out[0] = (float)total;
    }
}

extern "C" void kernel_launch(void* const* d_in, const int* in_sizes, int n_in,
                              void* d_out, int out_size, void* d_ws, size_t ws_size,
                              hipStream_t stream) {
    const float* pred = (const float*)d_in[0];
    const float* targ = (const float*)d_in[1];
    float* out = (float*)d_out;

    float* ws_sums = (float*)d_ws;                                        // 4*GBLK floats
    unsigned* ws_mins = (unsigned*)((char*)d_ws + sizeof(float) * 4 * GBLK);  // 2*GBLK uints

    yolo_main_kernel<<<GBLK, 64, 0, stream>>>(pred, targ, ws_sums, ws_mins);
    yolo_finalize_kernel<<<1, 1024, 0, stream>>>(pred, targ, ws_sums, ws_mins, out);
}

// Round 7
// 41.418 us; speedup vs baseline: 16.1467x; 1.0032x over previous
//
#include <hip/hip_runtime.h>
#include <stdint.h>

// YOLO v1 loss: BATCH=16384, S=7, B=2, C=20, D=30 floats per cell.
// NCELLS = 802816 = 12544 tiles * 64 cells.
// Main: 1280 persistent 1-wave blocks (5/CU exactly resident), double-buffered
// LDS pipeline with counted vmcnt (no barriers, no full drains in steady state).
#define NTILES 12544
#define GBLK 1280            // main blocks; also the partial count (= 5 * 256 CUs)
#define F4_PER_TILE 480      // 64 cells * 30 floats / 4 floats-per-float4

// async global->LDS, 16B per lane. LDS dest = wave-uniform base + lane*16.
#define ASYNC_CP16(gsrc, ldst)                                                     \
    __builtin_amdgcn_global_load_lds(                                              \
        (const __attribute__((address_space(1))) unsigned int*)(gsrc),             \
        (__attribute__((address_space(3))) unsigned int*)(ldst), 16, 0, 0)

__device__ __forceinline__ void merge2(unsigned& a1, unsigned& a2,
                                       unsigned b1, unsigned b2) {
    // (a1<=a2), (b1<=b2) -> two smallest of the union
    const unsigned n1 = min(a1, b1);
    const unsigned n2 = min(max(a1, b1), min(a2, b2));
    a1 = n1; a2 = n2;
}

// 16 fill instructions per tile (7 full-wave + 1 half-wave, x2 tensors)
__device__ __forceinline__ void issue_tile_fills(
    const float* __restrict__ pred, const float* __restrict__ targ,
    int tile, float* sp, float* st, int lane)
{
    const float4* p4 = reinterpret_cast<const float4*>(pred) + (size_t)tile * F4_PER_TILE;
    const float4* t4 = reinterpret_cast<const float4*>(targ) + (size_t)tile * F4_PER_TILE;
#pragma unroll
    for (int q = 0; q < 7; ++q) {
        ASYNC_CP16(p4 + lane + 64 * q, sp + 256 * q);
        ASYNC_CP16(t4 + lane + 64 * q, st + 256 * q);
    }
    if (lane < 32) {
        ASYNC_CP16(p4 + lane + 448, sp + 1792);
        ASYNC_CP16(t4 + lane + 448, st + 1792);
    }
}

// ws layout (SoA, every slot written every call):
//   float sums[4][GBLK]  at float offset 0       (loc_sq, hit, noobj, cls)
//   uint  mins[2][GBLK]  at float offset 4*GBLK  (min, second-min contained idx)

__global__ __launch_bounds__(64) void yolo_main_kernel(
    const float* __restrict__ pred, const float* __restrict__ targ,
    float* __restrict__ ws_sums, unsigned* __restrict__ ws_mins)
{
    // two buffers of (1920 pred + 1920 targ) floats = 30720 B total
    __shared__ __align__(16) float smem[7680];

    const int lane = threadIdx.x;       // 0..63, single wave
    const int blk  = blockIdx.x;
    const int n    = (blk < (NTILES - 9 * GBLK)) ? 10 : 9;   // tiles for this block

    float acc_loc = 0.0f, acc_hit = 0.0f, acc_noobj = 0.0f, acc_cls = 0.0f;
    unsigned m1 = 0xFFFFFFFFu, m2 = 0xFFFFFFFFu;

    // ---- prologue: fill both buffers (tiles r=0,1) ----
    issue_tile_fills(pred, targ, blk,        smem,        smem + 1920, lane);
    issue_tile_fills(pred, targ, blk + GBLK, smem + 3840, smem + 5760, lane);

    for (int r = 0; r < n; ++r) {
        float* sp = smem + (r & 1) * 3840;
        float* st = sp + 1920;

        // current tile's 16 fills landed; next tile's 16 may stay in flight
        if (r < n - 1) asm volatile("s_waitcnt vmcnt(16)" ::: "memory");
        else           asm volatile("s_waitcnt vmcnt(0)"  ::: "memory");
        __builtin_amdgcn_sched_barrier(0);

        // ---- read this thread's 30+30 floats from LDS ----
        float pv[30], tv[30];
        const float2* spp = reinterpret_cast<const float2*>(sp) + lane * 15;
        const float2* stp = reinterpret_cast<const float2*>(st) + lane * 15;
#pragma unroll
        for (int i = 0; i < 15; ++i) { float2 v = spp[i]; pv[2*i] = v.x; pv[2*i+1] = v.y; }
#pragma unroll
        for (int i = 0; i < 15; ++i) { float2 v = stp[i]; tv[2*i] = v.x; tv[2*i+1] = v.y; }

        // ds_reads retired -> safe to overwrite this buffer with tile r+2 fills
        asm volatile("s_waitcnt lgkmcnt(0)" ::: "memory");
        __builtin_amdgcn_sched_barrier(0);
        if (r < n - 2)
            issue_tile_fills(pred, targ, blk + (r + 2) * GBLK, sp, st, lane);

        const int cell = (blk + r * GBLK) * 64 + lane;
        const float obj = (tv[0] == 1.0f) ? 1.0f : 0.0f;

        // ---- class loss ----
        float cls = 0.0f;
#pragma unroll
        for (int i = 10; i < 30; ++i) { float d = pv[i] - tv[i]; cls = fmaf(d, d, cls); }
        acc_cls = fmaf(cls, obj, acc_cls);

        // ---- gt box 0 corners (mirrors reference arithmetic) ----
        const float g0x = tv[2] / 7.0f - 0.5f * tv[4];
        const float g0y = tv[3] / 7.0f - 0.5f * tv[5];
        const float g1x = tv[2] / 7.0f + 0.5f * tv[4];
        const float g1y = tv[3] / 7.0f + 0.5f * tv[5];
        const float area_g = (g1x - g0x) * (g1y - g0y);

        // ---- IoUs for both pred boxes vs gt box 0 ----
        float iou[2];
#pragma unroll
        for (int b = 0; b < 2; ++b) {
            const float px = pv[2 + 4*b], py = pv[3 + 4*b];
            const float pw = pv[4 + 4*b], ph = pv[5 + 4*b];
            const float a0x = px / 7.0f - 0.5f * pw, a0y = py / 7.0f - 0.5f * ph;
            const float a1x = px / 7.0f + 0.5f * pw, a1y = py / 7.0f + 0.5f * ph;
            const float ltx = fmaxf(a0x, g0x), lty = fmaxf(a0y, g0y);
            const float rbx = fminf(a1x, g1x), rby = fminf(a1y, g1y);
            const float ww = fmaxf(rbx - ltx, 0.0f), hh = fmaxf(rby - lty, 0.0f);
            const float inter  = ww * hh;
            const float area_a = (a1x - a0x) * (a1y - a0y);
            iou[b] = inter / (area_a + area_g - inter);
        }
        // jnp.argmax tie-break: first index wins
        const int resp = (iou[1] > iou[0]) ? 1 : 0;

#pragma unroll
        for (int b = 0; b < 2; ++b) {
            const bool m = (obj != 0.0f) && (b == resp);
            const float pc = pv[b];
            if (m) {
                const float d = pc - iou[b];
                acc_hit = fmaf(d, d, acc_hit);
                float sq = 0.0f;
#pragma unroll
                for (int i = 0; i < 4; ++i) {
                    const float a = pv[2 + 4*b + i], g = tv[2 + 4*b + i];
                    const float ds = sqrtf(a) - sqrtf(g);
                    sq = fmaf(ds, ds, sq);
                }
                acc_loc += sq;
                merge2(m1, m2, (unsigned)(cell * 2 + b), 0xFFFFFFFFu);
            } else {
                acc_noobj = fmaf(pc, pc, acc_noobj);
            }
        }
    }

    // ---- in-wave butterfly reduction (no LDS, no barriers) ----
#pragma unroll
    for (int mask = 32; mask > 0; mask >>= 1) {
        acc_loc   += __shfl_xor(acc_loc,   mask);
        acc_hit   += __shfl_xor(acc_hit,   mask);
        acc_noobj += __shfl_xor(acc_noobj, mask);
        acc_cls   += __shfl_xor(acc_cls,   mask);
        const unsigned b1 = (unsigned)__shfl_xor((int)m1, mask);
        const unsigned b2 = (unsigned)__shfl_xor((int)m2, mask);
        merge2(m1, m2, b1, b2);
    }
    if (lane == 0) {
        ws_sums[0 * GBLK + blk] = acc_loc;
        ws_sums[1 * GBLK + blk] = acc_hit;
        ws_sums[2 * GBLK + blk] = acc_noobj;
        ws_sums[3 * GBLK + blk] = acc_cls;
        ws_mins[0 * GBLK + blk] = m1;
        ws_mins[1 * GBLK + blk] = m2;
    }
}

__global__ __launch_bounds__(1024) void yolo_finalize_kernel(
    const float* __restrict__ pred, const float* __restrict__ targ,
    const float* __restrict__ ws_sums, const unsigned* __restrict__ ws_mins,
    float* __restrict__ out)
{
    const int tid = threadIdx.x;
    double s0 = 0.0, s1 = 0.0, s2 = 0.0, s3 = 0.0;
    unsigned m1 = 0xFFFFFFFFu, m2 = 0xFFFFFFFFu;
    for (int i = tid; i < GBLK; i += 1024) {
        s0 += (double)ws_sums[0 * GBLK + i];
        s1 += (double)ws_sums[1 * GBLK + i];
        s2 += (double)ws_sums[2 * GBLK + i];
        s3 += (double)ws_sums[3 * GBLK + i];
        merge2(m1, m2, ws_mins[0 * GBLK + i], ws_mins[1 * GBLK + i]);
    }
    __shared__ double dred[4][1024];
    __shared__ unsigned fm1[1024], fm2[1024];
    dred[0][tid] = s0; dred[1][tid] = s1; dred[2][tid] = s2; dred[3][tid] = s3;
    fm1[tid] = m1; fm2[tid] = m2;
    __syncthreads();
#pragma unroll
    for (int s = 512; s > 0; s >>= 1) {
        if (tid < s) {
            dred[0][tid] += dred[0][tid + s];
            dred[1][tid] += dred[1][tid + s];
            dred[2][tid] += dred[2][tid + s];
            dred[3][tid] += dred[3][tid + s];
            unsigned a1 = fm1[tid], a2 = fm2[tid];
            merge2(a1, a2, fm1[tid + s], fm2[tid + s]);
            fm1[tid] = a1; fm2[tid] = a2;
        }
        __syncthreads();
    }
    if (tid == 0) {
        double loc = dred[0][0];
        const double hit = dred[1][0], noobj = dred[2][0], cls = dred[3][0];
        const unsigned mm[2] = { fm1[0], fm2[0] };
        // first two responsible boxes (global flat order) use plain instead of sq
#pragma unroll
        for (int s = 0; s < 2; ++s) {
            const unsigned idx = mm[s];
            if (idx != 0xFFFFFFFFu) {
                const int cell = (int)(idx >> 1);
                const int b    = (int)(idx & 1u);
                const float* p = pred + (size_t)cell * 30 + 2 + 4*b;
                const float* t = targ + (size_t)cell * 30 + 2 + 4*b;
                float plain = 0.0f, sq = 0.0f;
#pragma unroll
                for (int i = 0; i < 4; ++i) {
                    const float a = p[i], g = t[i];
                    const float dd = a - g;  plain = fmaf(dd, dd, plain);
                    const float ds = sqrtf(a) - sqrtf(g); sq = fmaf(ds, ds, sq);
                }
                loc += (double)plain - (double)sq;
            }
        }
        const double total = (5.0 * loc + hit + 0.5 * noobj + cls) / 16384.0;
        out[0] = (float)total;
    }
}

extern "C" void kernel_launch(void* const* d_in, const int* in_sizes, int n_in,
                              void* d_out, int out_size, void* d_ws, size_t ws_size,
                              hipStream_t stream) {
    const float* pred = (const float*)d_in[0];
    const float* targ = (const float*)d_in[1];
    float* out = (float*)d_out;

    float* ws_sums = (float*)d_ws;                                        // 4*GBLK floats
    unsigned* ws_mins = (unsigned*)((char*)d_ws + sizeof(float) * 4 * GBLK);  // 2*GBLK uints

    yolo_main_kernel<<<GBLK, 64, 0, stream>>>(pred, targ, ws_sums, ws_mins);
    yolo_finalize_kernel<<<1, 1024, 0, stream>>>(pred, targ, ws_sums, ws_mins, out);
}